// Round 5
// baseline (724.324 us; speedup 1.0000x reference)
//
#include <hip/hip_runtime.h>
#include <hip/hip_bf16.h>

#define NUM_ADC_P 8
#define DENSE_L   1024
#define L_TILDE   64

#define M_TILE    64                      // rows per block
#define K_STEP    128                     // floats staged per step
#define N_STEPS   (DENSE_L / K_STEP)      // 8

typedef __attribute__((ext_vector_type(8))) short  short8;   // 8 bf16 (MFMA A/B frag)
typedef __attribute__((ext_vector_type(4))) float  float4v;  // MFMA C/D frag

// ws layout: [0, 128 KiB) = wt bf16[64][1024]  (Wt = W^T, n-major)

// ---------------------------------------------------------------------------
// Kernel 1: Wt[n][k] = bf16(exp(-((k+1)-w_n)^2/100)), n-major. Full matrix:
// far-off entries round to exact bf16 zero -> branch-free GEMM, identical
// numerics.
// ---------------------------------------------------------------------------
__global__ void build_w(const float* __restrict__ weight,
                        __hip_bfloat16* __restrict__ wt) {
    const int n = blockIdx.x;
    const float wn = weight[n];
    for (int k = threadIdx.x; k < DENSE_L; k += blockDim.x) {
        const float t = (float)(k + 1);
        const float d = t - wn;
        wt[n * DENSE_L + k] = __float2bfloat16(expf(-d * d * 0.01f));
    }
}

// ---------------------------------------------------------------------------
// 8x fp32 -> bf16 via packed HW convert (v_cvt_pk_bf16_f32 on gfx950).
// ---------------------------------------------------------------------------
__device__ __forceinline__ short8 cvt8(float4v a, float4v b) {
    union { short8 s; __hip_bfloat162 h[4]; } u;
    u.h[0] = __float22bfloat162_rn(make_float2(a[0], a[1]));
    u.h[1] = __float22bfloat162_rn(make_float2(a[2], a[3]));
    u.h[2] = __float22bfloat162_rn(make_float2(b[0], b[1]));
    u.h[3] = __float22bfloat162_rn(make_float2(b[2], b[3]));
    return u.s;
}

// async global->LDS, 16 B per lane; LDS dest = wave-uniform base + lane*16
__device__ __forceinline__ void gload_lds16(const float* src, float* lds_dst) {
    __builtin_amdgcn_global_load_lds(
        (const __attribute__((address_space(1))) unsigned int*)src,
        (__attribute__((address_space(3))) unsigned int*)lds_dst,
        16, 0, 0);
}

// ---------------------------------------------------------------------------
// Kernel 2: C[M,64] = A[M,1024] * W[1024,64], bf16 MFMA fp32-acc.
//
// LDS-staged A via global_load_lds (canonical §5 structure).
// The register-direct kernel read each 4-KiB A row in 32 separate 128-B
// chunks interleaved across 32 rows/wave x 4096 waves -> DRAM page thrash,
// measured ~1.7 TB/s (27% of achievable) regardless of waitcnt structure.
// Now each stage instruction reads two full 512-B row-chunks contiguously
// (8 visits/row instead of 32), direct to LDS (no VGPR roundtrip).
//
// Per-step schedule (m97 2-phase):
//   [16 B-frag loads (L1-resident Wt)] -> [8 global_load_lds for step+1]
//   -> [4 k-slabs: 2x ds_read_b128 A, cvt8, 4 MFMA] -> __syncthreads()
// B loads are OLDER than stage loads in the vmcnt FIFO, so B-waits are
// counted and the stage drains only at the pre-barrier vmcnt(0)
// -> stage latency hidden under compute.
//
// LDS: A fp32 [2][64][128] = 2 x 32 KiB -> 2 blocks/CU (8 waves).
// ds_read of A frags is ~16-way bank-conflicted (row stride 512 B) but LDS
// throughput math clears the HBM-bound target by >6x; swizzle deliberately
// omitted (minimize bug surface; revisit only if counters show LDS-bound).
//
// Fragment layout (verified, absmax 0.125):
//   A frag: lane holds A[mw + (lane&15)][32*ks + (lane>>4)*8 + j], j=0..7
//   B frag: lane holds Wt[n0 + (lane&15)][32*ks + (lane>>4)*8 + j]
//   D frag: D[mw + (lane>>4)*4 + rr][n0 + (lane&15)], rr=0..3
// ---------------------------------------------------------------------------
__global__ __launch_bounds__(256, 2)
void sampling_gemm(const float* __restrict__ x,
                   const __hip_bfloat16* __restrict__ wt,
                   float* __restrict__ out) {
    __shared__ float A_lds[2][M_TILE * K_STEP];   // 2 x 32 KiB

    const int lane = threadIdx.x & 63;
    const int w    = threadIdx.x >> 6;            // wave 0..3
    const int r    = lane & 15;
    const int q    = lane >> 4;                   // quad 0..3
    const int half = lane >> 5;                   // 0/1: which row of the pair
    const int lc   = lane & 31;                   // 16-B column within 512-B chunk

    const long m0 = (long)blockIdx.x * M_TILE;    // block row base
    const long mw = m0 + (long)w * 16;            // wave row base (16 rows/wave)

    const short* w0 = (const short*)wt + r * DENSE_L + q * 8;

    float4v acc[4];
    #pragma unroll
    for (int n = 0; n < 4; ++n) acc[n] = (float4v){0.f, 0.f, 0.f, 0.f};

    // stage: wave w fills its own 16 rows (2 rows per instruction)
    auto stage = [&](int step, int buf) {
        #pragma unroll
        for (int i = 0; i < 8; ++i) {
            const long row = mw + i * 2 + half;                       // per-lane row
            const float* src = x + row * DENSE_L + step * K_STEP + lc * 4;
            float* dst = &A_lds[buf][(w * 16 + i * 2) * K_STEP];      // wave-uniform
            gload_lds16(src, dst);
        }
    };

    // prologue: stage step 0; barrier drains vmcnt and publishes LDS
    stage(0, 0);
    __syncthreads();

    int cur = 0;
    for (int step = 0; step < N_STEPS; ++step) {
        // (1) all 16 B-fragment loads for this step (oldest in vmcnt FIFO)
        short8 bfr[4][4];                          // [slab][n-subtile]
        #pragma unroll
        for (int s = 0; s < 4; ++s) {
            const short* wk = w0 + (step * 4 + s) * 32;
            #pragma unroll
            for (int n = 0; n < 4; ++n)
                bfr[s][n] = *(const short8*)(wk + n * 16 * DENSE_L);
        }

        // (2) stage NEXT step (newest in FIFO -> never waited before barrier)
        if (step < N_STEPS - 1)
            stage(step + 1, cur ^ 1);

        // (3) compute 4 k-slabs from LDS
        #pragma unroll
        for (int s = 0; s < 4; ++s) {
            const float* ap = &A_lds[cur][(w * 16 + r) * K_STEP + s * 32 + q * 8];
            const float4v alo = *(const float4v*)ap;
            const float4v ahi = *(const float4v*)(ap + 4);
            const short8 af = cvt8(alo, ahi);
            acc[0] = __builtin_amdgcn_mfma_f32_16x16x32_bf16(af, bfr[s][0], acc[0], 0, 0, 0);
            acc[1] = __builtin_amdgcn_mfma_f32_16x16x32_bf16(af, bfr[s][1], acc[1], 0, 0, 0);
            acc[2] = __builtin_amdgcn_mfma_f32_16x16x32_bf16(af, bfr[s][2], acc[2], 0, 0, 0);
            acc[3] = __builtin_amdgcn_mfma_f32_16x16x32_bf16(af, bfr[s][3], acc[3], 0, 0, 0);
        }

        // (4) barrier: drains stage vmcnt (hidden under (3)) + buffer handoff
        __syncthreads();
        cur ^= 1;
    }

    // Epilogue: D[mw + q*4 + rr][ns*16 + r]; streaming stores.
    #pragma unroll
    for (int ns = 0; ns < 4; ++ns) {
        #pragma unroll
        for (int rr = 0; rr < 4; ++rr) {
            __builtin_nontemporal_store(
                acc[ns][rr],
                out + (mw + q * 4 + rr) * L_TILDE + ns * 16 + r);
        }
    }
}

// ---------------------------------------------------------------------------
extern "C" void kernel_launch(void* const* d_in, const int* in_sizes, int n_in,
                              void* d_out, int out_size, void* d_ws, size_t ws_size,
                              hipStream_t stream) {
    const float* x      = (const float*)d_in[0];   // [B, P*L] fp32
    const float* weight = (const float*)d_in[1];   // [64] fp32
    float* out          = (float*)d_out;           // [B, P*64] fp32
    __hip_bfloat16* wt  = (__hip_bfloat16*)d_ws;   // [64][1024] bf16 = 128 KiB

    const int M = in_sizes[0] / DENSE_L;           // B * NUM_ADC_P = 131072
    const int grid = M / M_TILE;                   // 2048 blocks

    build_w<<<64, 256, 0, stream>>>(weight, wt);
    sampling_gemm<<<grid, 256, 0, stream>>>(x, wt, out);
}